// Round 1
// baseline (708.771 us; speedup 1.0000x reference)
//
#include <hip/hip_runtime.h>
#include <stdint.h>

// Problem constants
#define B_DIM 2
#define S_DIM 512
#define N_DIM 256
#define F_DIM 362
#define D_DIM 128
#define M_DIM (B_DIM * S_DIM * N_DIM)  // 262144 rows
#define KPAD 384                       // 361 shared-K padded to 12*32
#define NKC (KPAD / 32)                // 12 K-chunks
#define BM 64                          // rows per block

typedef float f32x4 __attribute__((ext_vector_type(4)));
typedef __bf16 bf16x8 __attribute__((ext_vector_type(8)));
typedef unsigned short u16x4 __attribute__((ext_vector_type(4)));

__device__ __forceinline__ unsigned short f2bf(float f) {
  union { float f; unsigned u; } c; c.f = f;
  unsigned u = c.u;
  return (unsigned short)((u + 0x7FFFu + ((u >> 16) & 1u)) >> 16);  // RNE
}

// ---------------- P1: Haar DWT + linear interp on feature 0 ----------------
// One wave per (b,n): loads x[b, :, n, 0] (512 values), computes cA/cD (256
// each), interpolates back to 512, writes Xl_ws/Xh_ws laid out as [b,s,n].
__global__ __launch_bounds__(256) void haar_kernel(const float* __restrict__ x,
                                                   float* __restrict__ Xl,
                                                   float* __restrict__ Xh) {
  __shared__ float cA[4][256];
  __shared__ float cD[4][256];
  int tid = threadIdx.x;
  int wid = tid >> 6, lane = tid & 63;
  int gw = blockIdx.x * 4 + wid;  // 0..511
  int b = gw >> 8, n = gw & 255;
  const float* xp = x + ((size_t)b * S_DIM * N_DIM + n) * F_DIM;
  float r[8];
#pragma unroll
  for (int j = 0; j < 8; ++j) {
    int s = lane * 8 + j;
    r[j] = xp[(size_t)s * (N_DIM * F_DIM)];
  }
  const float is2 = 0.70710678118654752440f;
#pragma unroll
  for (int jj = 0; jj < 4; ++jj) {
    int i = lane * 4 + jj;
    cA[wid][i] = (r[2 * jj] + r[2 * jj + 1]) * is2;
    cD[wid][i] = (r[2 * jj] - r[2 * jj + 1]) * is2;
  }
  __syncthreads();
  float* xlp = Xl + (size_t)b * S_DIM * N_DIM + n;
  float* xhp = Xh + (size_t)b * S_DIM * N_DIM + n;
#pragma unroll
  for (int j = 0; j < 8; ++j) {
    int s = lane * 8 + j;
    float src = fmaxf(0.5f * (float)s - 0.25f, 0.0f);
    int i0 = (int)src;               // floor (src >= 0)
    float w = src - (float)i0;
    int i1 = min(i0 + 1, 255);
    float a0 = cA[wid][i0], a1 = cA[wid][i1];
    float d0 = cD[wid][i0], d1 = cD[wid][i1];
    xlp[(size_t)s * N_DIM] = a0 + w * (a1 - a0);
    xhp[(size_t)s * N_DIM] = d0 + w * (d1 - d0);
  }
}

// ---------------- P2: weights -> bf16 swizzled B fragments ----------------
// Bswz[(((proj*NKC + kc)*8 + nb)*64 + lane)*8 + j] = W[d*362 + kk] (bf16)
// with d = nb*16 + (lane&15), kk = kc*32 + (lane>>4)*8 + j, zero for kk>360.
// Also writes w361[proj*128 + d] = W[d*362 + 361] (fp32, rank-1 column).
__global__ __launch_bounds__(256) void prep_kernel(const float* __restrict__ Wg,
                                                   const float* __restrict__ Wh,
                                                   unsigned short* __restrict__ Bswz,
                                                   float* __restrict__ w361) {
  int t = blockIdx.x * 256 + threadIdx.x;
  const int NFRAG = 2 * NKC * 8 * 64;  // 12288
  if (t < NFRAG) {
    int l = t & 63;
    int t2 = t >> 6;
    int nb = t2 & 7;
    int t3 = t2 >> 3;
    int kc = t3 % NKC;
    int proj = t3 / NKC;
    const float* W = proj ? Wh : Wg;
    int d = nb * 16 + (l & 15);
    int kkb = kc * 32 + (l >> 4) * 8;
    unsigned short* o = Bswz + (size_t)t * 8;
#pragma unroll
    for (int j = 0; j < 8; ++j) {
      int kk = kkb + j;
      float v = (kk < 361) ? W[d * F_DIM + kk] : 0.0f;
      o[j] = f2bf(v);
    }
  } else {
    int tw = t - NFRAG;
    if (tw < 256) {
      w361[tw] = (tw < 128) ? Wg[tw * F_DIM + 361]
                            : Wh[(tw - 128) * F_DIM + 361];
    }
  }
}

// ---------------- Main: dual GEMM + rank-1 + bias epilogue ----------------
// Block = 256 threads (4 waves), BM=64 rows. Stage A (features 1..361 as
// bf16, K padded to 384) into XOR-swizzled LDS once; 12 K-chunk MFMA loop.
// Wave w owns col-blocks nb0=2w, 2w+1 for BOTH projections, all 64 rows.
__global__ __launch_bounds__(256, 3) void gemm_kernel(
    const float* __restrict__ x, const unsigned short* __restrict__ Bswz,
    const float* __restrict__ Xl, const float* __restrict__ Xh,
    const float* __restrict__ w361, const float* __restrict__ bg,
    const float* __restrict__ bh, float* __restrict__ out) {
  __shared__ unsigned short A_lds[BM * KPAD];  // 48 KiB, swizzled bf16
  int tid = threadIdx.x;
  int m0 = blockIdx.x * BM;

  // ---- stage A: thread = (row r, quarter p), loads 96 floats of x row ----
  {
    int r = tid >> 2, p = tid & 3;
    const float* src = x + (size_t)(m0 + r) * F_DIM + 1 + p * 96;
    unsigned sw = (unsigned)((r & 7) << 4);
    char* rowbase = (char*)A_lds + (size_t)r * (KPAD * 2);
#pragma unroll
    for (int i = 0; i < 24; ++i) {
      int kkb = p * 96 + i * 4;  // A col of first element
      float v[4];
      if (kkb <= 357) {
        __builtin_memcpy(v, src + i * 4, 16);  // features kkb+1 .. kkb+4
      } else if (kkb == 360) {
        v[0] = src[i * 4];  // feature 361 (last valid)
        v[1] = v[2] = v[3] = 0.0f;
      } else {
        v[0] = v[1] = v[2] = v[3] = 0.0f;  // zero-pad K 361..383
      }
      u16x4 w4;
      w4[0] = f2bf(v[0]); w4[1] = f2bf(v[1]);
      w4[2] = f2bf(v[2]); w4[3] = f2bf(v[3]);
      *(u16x4*)(rowbase + (((unsigned)(kkb * 2)) ^ sw)) = w4;
    }
  }
  __syncthreads();

  int lane = tid & 63, wid = tid >> 6;
  int nb0 = wid * 2;
  int l15 = lane & 15, lhi = lane >> 4;
  int lhi16 = lhi * 16;

  f32x4 acc[4][2][2] = {};  // [row-tile][nbi][proj]

  unsigned rowB[4], swv[4];
#pragma unroll
  for (int rt = 0; rt < 4; ++rt) {
    int row = rt * 16 + l15;
    rowB[rt] = (unsigned)(row * (KPAD * 2));
    swv[rt] = (unsigned)((row & 7) << 4);
  }
  const unsigned short* bk0 = Bswz + (size_t)lane * 8;

#pragma unroll
  for (int kc = 0; kc < NKC; ++kc) {
    bf16x8 a[4];
#pragma unroll
    for (int rt = 0; rt < 4; ++rt) {
      unsigned off = rowB[rt] + (((unsigned)(kc * 64 + lhi16)) ^ swv[rt]);
      a[rt] = *(const bf16x8*)((const char*)A_lds + off);
    }
    bf16x8 bfr[2][2];
#pragma unroll
    for (int proj = 0; proj < 2; ++proj)
#pragma unroll
      for (int nbi = 0; nbi < 2; ++nbi)
        bfr[nbi][proj] = *(const bf16x8*)(bk0 +
            ((size_t)(proj * NKC + kc) * 8 + (nb0 + nbi)) * 512);
#pragma unroll
    for (int rt = 0; rt < 4; ++rt)
#pragma unroll
      for (int nbi = 0; nbi < 2; ++nbi)
#pragma unroll
        for (int proj = 0; proj < 2; ++proj)
          acc[rt][nbi][proj] = __builtin_amdgcn_mfma_f32_16x16x32_bf16(
              a[rt], bfr[nbi][proj], acc[rt][nbi][proj], 0, 0, 0);
  }

  // ---- epilogue: + Xl/Xh * W[:,361] + bias, fp32 exact ----
  float wg1[2], wh1[2], bgv[2], bhv[2];
#pragma unroll
  for (int nbi = 0; nbi < 2; ++nbi) {
    int d = (nb0 + nbi) * 16 + l15;
    wg1[nbi] = w361[d];
    wh1[nbi] = w361[128 + d];
    bgv[nbi] = bg[d];
    bhv[nbi] = bh[d];
  }
  float* outl = out;
  float* outh = out + (size_t)M_DIM * D_DIM;
#pragma unroll
  for (int rt = 0; rt < 4; ++rt) {
#pragma unroll
    for (int reg = 0; reg < 4; ++reg) {
      int m = m0 + rt * 16 + lhi * 4 + reg;  // D row = (lane>>4)*4 + reg
      float xl = Xl[m], xh = Xh[m];
      size_t rowoff = (size_t)m * D_DIM;
#pragma unroll
      for (int nbi = 0; nbi < 2; ++nbi) {
        int d = (nb0 + nbi) * 16 + l15;  // D col = lane&15
        outl[rowoff + d] = acc[rt][nbi][0][reg] + xl * wg1[nbi] + bgv[nbi];
        outh[rowoff + d] = acc[rt][nbi][1][reg] + xh * wh1[nbi] + bhv[nbi];
      }
    }
  }
}

extern "C" void kernel_launch(void* const* d_in, const int* in_sizes, int n_in,
                              void* d_out, int out_size, void* d_ws,
                              size_t ws_size, hipStream_t stream) {
  const float* x = (const float*)d_in[0];
  const float* Wg_w = (const float*)d_in[1];
  const float* Wg_b = (const float*)d_in[2];
  const float* Wh_w = (const float*)d_in[3];
  const float* Wh_b = (const float*)d_in[4];
  float* out = (float*)d_out;

  char* ws = (char*)d_ws;
  float* Xl = (float*)ws;                                   // M floats (1 MiB)
  float* Xh = (float*)(ws + (size_t)M_DIM * 4);             // M floats (1 MiB)
  unsigned short* Bswz = (unsigned short*)(ws + (size_t)2 * M_DIM * 4);  // 192 KiB
  float* w361 = (float*)(ws + (size_t)2 * M_DIM * 4 + 2 * NKC * 8 * 512 * 2);

  haar_kernel<<<128, 256, 0, stream>>>(x, Xl, Xh);
  prep_kernel<<<49, 256, 0, stream>>>(Wg_w, Wh_w, Bswz, w361);
  gemm_kernel<<<M_DIM / BM, 256, 0, stream>>>(x, Bswz, Xl, Xh, w361, Wg_b,
                                              Wh_b, out);
}